// Round 17
// baseline (1026.734 us; speedup 1.0000x reference)
//
#include <hip/hip_runtime.h>
#include <math.h>

// ---------------------------------------------------------------------------
// CapsuleNet forward (round 17): fuse priors+routing into routing3_k.
// Key insight: rw as fp16 = 2.95 MB -> fully L2-resident per XCD. So the
// 189 MB priors buffer (written by priors_k, read by routing2_k) is pure
// waste: compute priors in-register inside routing. ut relaid [b][n][8]
// (block-contiguous, coalesced frag8 reads; also better squash writes).
// prep_k additionally emits rwh (rw fp32->fp16). 9 -> 8 dispatches.
// prim parked at round-7 body / (256,4) (rounds 8/9/10/15 all lost).
// ---------------------------------------------------------------------------

typedef _Float16 h16;
typedef h16 frag8 __attribute__((ext_vector_type(8)));    // 8 halves = 16 B
typedef float f32x4 __attribute__((ext_vector_type(4)));

// workspace layout (BYTE offsets).
#define OFFB_HHI   0L             // 52428800 halves = 104857600 B
#define OFFB_RWH   104857600L     // 1474560 halves = 2949120 B (rw fp16)
#define OFFB_UT    188743680L     // 4718592 halves = 9437184 B (ut[b][n][8])
#define OFFB_WTHI  209715200L     // 5308416 halves = 10616832 B
#define OFFB_WT1   230948864L     // w1t: 24576 halves = 49152 B
#define OFFB_C     231031808L     // 4718592 floats -> end 249906176
#define WS_BYTES   249906176L
// aliased into dead wt region after prim_gemm (wthi dead once prim done):
#define OFFB_V     209715200L     // 81920 floats (vbuf)
#define OFFB_D1    210370560L     // 262144 floats
#define OFFB_D2    211419136L     // 524288 floats -> 213516288 OK

// --------------------------------------------------------------------------
// prep: 0..95 w1t[oc][96] fp16; 96..351 prim B^T fp16; 352..6111 rwh fp16;
// 6112..24543 zero C.
__global__ __launch_bounds__(256) void prep_k(const float* __restrict__ w1,
                                              const float* __restrict__ pw,
                                              const float* __restrict__ rw,
                                              h16* __restrict__ w1t,
                                              h16* __restrict__ whi,
                                              h16* __restrict__ rwh,
                                              float* __restrict__ C) {
    __shared__ float s[2592];
    int bx = blockIdx.x, tid = threadIdx.x;
    if (bx < 96) {
        int k = bx, oc = tid;
        w1t[(long)oc * 96 + k] = (k < 81) ? (h16)w1[oc * 81 + k] : (h16)0.f;
    } else if (bx < 352) {
        int oc = bx - 96;
        long src0 = (long)oc * 20736, dst0 = src0;
        for (int ch = 0; ch < 8; ++ch) {
            int ic0 = ch * 32;
            __syncthreads();
            for (int e = tid; e < 2592; e += 256) s[e] = pw[src0 + ic0 * 81 + e];
            __syncthreads();
            for (int e = tid; e < 2592; e += 256) {
                int tap = e >> 5, icf = e & 31;
                whi[dst0 + tap * 256 + ic0 + icf] = (h16)s[icf * 81 + tap];
            }
        }
    } else if (bx < 6112) {
        long i = (long)(bx - 352) * 256 + tid;   // 5760*256 = 1474560 exact
        rwh[i] = (h16)rw[i];
    } else {
        long i = (long)(bx - 6112) * 256 + tid;  // 18432*256 = 4718592 exact
        C[i] = 0.f;
    }
}

// --------------------------------------------------------------------------
// conv1 as MFMA implicit-im2col GEMM. Grid 3200: nt = bx&1, mt = bx>>1.
#define CLDK 104
__global__ __launch_bounds__(256, 2) void conv1_mfma(const float* __restrict__ x,
                                                     const h16* __restrict__ w1t,
                                                     const float* __restrict__ bias,
                                                     h16* __restrict__ hhi) {
    __shared__ h16 Al[128 * CLDK];
    __shared__ h16 Bw[128 * CLDK];
    int tid = threadIdx.x;
    int bx = blockIdx.x;
    int nt = bx & 1, mt = bx >> 1;
    int n0 = nt * 128;

    for (int e = tid; e < 128 * 96; e += 256) {
        int oc = e / 96, k = e - (e / 96) * 96;
        Bw[oc * CLDK + k] = w1t[(long)(n0 + oc) * 96 + k];
    }
    for (int e = tid; e < 128 * 96; e += 256) {
        int ml = e / 96, k = e - (e / 96) * 96;
        int m = mt * 128 + ml;
        int b = m / 400, pix = m - b * 400;
        int oy = pix / 20, ox = pix - oy * 20;
        float v = 0.f;
        if (k < 81) {
            int ky = k / 9, kx = k - ky * 9;
            v = x[(long)b * 784 + (oy + ky) * 28 + (ox + kx)];
        }
        Al[ml * CLDK + k] = (h16)v;
    }
    __syncthreads();

    int wave = tid >> 6;
    int wm = wave >> 1, wn = wave & 1;
    int lane = tid & 63;
    int lm = lane & 15, quad = lane >> 4;

    f32x4 acc[4][4];
#pragma unroll
    for (int i = 0; i < 4; ++i)
#pragma unroll
        for (int j = 0; j < 4; ++j) acc[i][j] = (f32x4){0.f, 0.f, 0.f, 0.f};

#pragma unroll
    for (int ks = 0; ks < 3; ++ks) {
        int kc = ks * 32 + quad * 8;
        frag8 af[4], bf[4];
#pragma unroll
        for (int mi = 0; mi < 4; ++mi)
            af[mi] = *(const frag8*)&Al[(wm * 64 + mi * 16 + lm) * CLDK + kc];
#pragma unroll
        for (int ni = 0; ni < 4; ++ni)
            bf[ni] = *(const frag8*)&Bw[(wn * 64 + ni * 16 + lm) * CLDK + kc];
#pragma unroll
        for (int mi = 0; mi < 4; ++mi)
#pragma unroll
            for (int ni = 0; ni < 4; ++ni)
                acc[mi][ni] = __builtin_amdgcn_mfma_f32_16x16x32_f16(
                    af[mi], bf[ni], acc[mi][ni], 0, 0, 0);
    }

#pragma unroll
    for (int ni = 0; ni < 4; ++ni) {
        int oc = n0 + wn * 64 + ni * 16 + lm;
        float bv = bias[oc];
#pragma unroll
        for (int mi = 0; mi < 4; ++mi) {
            int m = mt * 128 + wm * 64 + mi * 16 + quad * 4;
#pragma unroll
            for (int r = 0; r < 4; ++r)
                hhi[(long)(m + r) * 256 + oc] = (h16)fmaxf(acc[mi][ni][r] + bv, 0.f);
        }
    }
}

// --------------------------------------------------------------------------
// prim conv MFMA GEMM (round-7 body, proven 340 us): BM=128 BN=128 BK=32,
// split-K x8 (kt = bx&7 -> XCD-pinned B slice), fp16 single pass,
// register-prefetch staging, atomic accumulate into zeroed C. 4 waves/EU.
#define LDK 40
__global__ __launch_bounds__(256, 4) void prim_gemm_mfma(
        const h16* __restrict__ Ahi, const h16* __restrict__ Bhi,
        float* __restrict__ C) {
    __shared__ h16 As[128][LDK];
    __shared__ h16 Bs[128][LDK];
    int tid = threadIdx.x;
    int bx = blockIdx.x;                  // 2304 blocks
    int kt = bx & 7;
    int nt = (bx >> 3) & 1;
    int mt = bx >> 4;                     // 0..143
    int n0 = nt * 128;
    int kb0 = kt * 81;

    int wave = tid >> 6;
    int wm = wave >> 1, wn = wave & 1;
    int lane = tid & 63;
    int lm = lane & 15, quad = lane >> 4;

    int ra = tid >> 1;
    int sa = (tid & 1) * 16;
    int ma = mt * 128 + ra;
    int b = ma / 36, pos = ma - b * 36;
    int oy = pos / 6, ox = pos - oy * 6;
    long abase = ((long)(b * 20 + 2 * oy) * 20 + 2 * ox) * 256 + sa;
    long bbase = (long)(n0 + ra) * 20736 + sa;

    float4 pa0, pa1, pb0, pb1;
    auto gload = [&](int kb) {
        int tap = kb >> 3;
        int ic0 = (kb & 7) << 5;
        int ky = tap / 9, kx = tap - ky * 9;
        long aoff = abase + (ky * 20 + kx) * 256 + ic0;
        pa0 = *(const float4*)(Ahi + aoff);
        pa1 = *(const float4*)(Ahi + aoff + 8);
        long boff = bbase + (long)kb * 32;
        pb0 = *(const float4*)(Bhi + boff);
        pb1 = *(const float4*)(Bhi + boff + 8);
    };

    f32x4 acc[4][4];
#pragma unroll
    for (int i = 0; i < 4; ++i)
#pragma unroll
        for (int j = 0; j < 4; ++j) acc[i][j] = (f32x4){0.f, 0.f, 0.f, 0.f};

    gload(kb0);
    for (int it = 0; it < 81; ++it) {
        __syncthreads();
        *(float4*)&As[ra][sa]     = pa0;
        *(float4*)&As[ra][sa + 8] = pa1;
        *(float4*)&Bs[ra][sa]     = pb0;
        *(float4*)&Bs[ra][sa + 8] = pb1;
        __syncthreads();
        if (it + 1 < 81) gload(kb0 + it + 1);

        frag8 ah[4], bh[4];
#pragma unroll
        for (int mi = 0; mi < 4; ++mi) {
            int row = wm * 64 + mi * 16 + lm;
            ah[mi] = *(const frag8*)&As[row][quad * 8];
        }
#pragma unroll
        for (int ni = 0; ni < 4; ++ni) {
            int col = wn * 64 + ni * 16 + lm;
            bh[ni] = *(const frag8*)&Bs[col][quad * 8];
        }
#pragma unroll
        for (int mi = 0; mi < 4; ++mi)
#pragma unroll
            for (int ni = 0; ni < 4; ++ni)
                acc[mi][ni] = __builtin_amdgcn_mfma_f32_16x16x32_f16(
                    ah[mi], bh[ni], acc[mi][ni], 0, 0, 0);
    }

#pragma unroll
    for (int ni = 0; ni < 4; ++ni) {
        int n = n0 + wn * 64 + ni * 16 + lm;
#pragma unroll
        for (int mi = 0; mi < 4; ++mi) {
            int m = mt * 128 + wm * 64 + mi * 16 + quad * 4;
#pragma unroll
            for (int r = 0; r < 4; ++r)
                atomicAdd(&C[(long)(m + r) * 256 + n], acc[mi][ni][r]);
        }
    }
}

// --------------------------------------------------------------------------
// squash: C[(b*36+pos)][256] (+bias) -> ut[b][n][8] fp16, n = ci*36+pos.
// [b][n] layout: contiguous per-b slice (routing3 reads it coalesced).
__global__ void squash_k(const float* __restrict__ C,
                         const float* __restrict__ bias,
                         h16* __restrict__ ut) {
    int t = blockIdx.x * 256 + threadIdx.x;          // 589824 exact
    int row = t >> 5;                                 // (b*36+pos)
    int ci = t & 31;
    int b = row / 36, pos = row - b * 36;
    const float* src = C + (long)row * 256 + ci;
    float v[8]; float sn = 0.f;
#pragma unroll
    for (int i = 0; i < 8; ++i) {
        v[i] = src[i * 32] + bias[ci + i * 32];
        sn = fmaf(v[i], v[i], sn);
    }
    float scale = (sn / (1.f + sn)) / sqrtf(sn);
    frag8 o;
#pragma unroll
    for (int i = 0; i < 8; ++i) o[i] = (h16)(v[i] * scale);
    *(frag8*)(ut + ((long)b * 1152 + ci * 36 + pos) * 8) = o;
}

// --------------------------------------------------------------------------
// routing3: fused priors + 3-iter routing. Block per (c,b), 384 threads,
// 3 nodes/thread. Priors computed in-register from ut (coalesced frag8) and
// rwh (fp16 rw, 2.95 MB -> L2-resident on every XCD). No priors buffer.
// Iteration 0 uses the exact uniform-softmax shortcut (initial logits = 0).
__global__ __launch_bounds__(384) void routing3_k(const h16* __restrict__ ut,
                                                  const h16* __restrict__ rwh,
                                                  float* __restrict__ vbuf) {
    int c = blockIdx.x >> 9;
    int b = blockIdx.x & 511;
    int tid = threadIdx.x;
    int wid = tid >> 6;
    int lane = tid & 63;
    __shared__ float wred[6][20];

    float pr[3][16];
#pragma unroll
    for (int r = 0; r < 3; ++r) {
        int n = tid + r * 384;
        frag8 uv = *(const frag8*)(ut + ((long)b * 1152 + n) * 8);
        const frag8* wp = (const frag8*)(rwh + ((long)c * 1152 + n) * 128);
        float uu[8];
#pragma unroll
        for (int i = 0; i < 8; ++i) uu[i] = (float)uv[i];
        float o[16];
#pragma unroll
        for (int j = 0; j < 16; ++j) o[j] = 0.f;
#pragma unroll
        for (int i = 0; i < 8; ++i) {
            frag8 w0 = wp[i * 2], w1 = wp[i * 2 + 1];
#pragma unroll
            for (int j = 0; j < 8; ++j) {
                o[j]     = fmaf(uu[i], (float)w0[j], o[j]);
                o[j + 8] = fmaf(uu[i], (float)w1[j], o[j + 8]);
            }
        }
#pragma unroll
        for (int j = 0; j < 16; ++j) pr[r][j] = o[j];
    }

    float l0 = 0.f, l1 = 0.f, l2 = 0.f;
    float vout[16];

    // ---- iteration 0: probs uniform = 1/1152 ----
    {
        float red[16];
#pragma unroll
        for (int o = 0; o < 16; ++o) red[o] = pr[0][o] + pr[1][o] + pr[2][o];
#pragma unroll
        for (int o = 0; o < 16; ++o) {
#pragma unroll
            for (int m = 32; m >= 1; m >>= 1) red[o] += __shfl_xor(red[o], m);
        }
        if (lane == 0) {
#pragma unroll
            for (int o = 0; o < 16; ++o) wred[wid][o] = red[o];
        }
        __syncthreads();
        float inv = 1.f / 1152.f;
        float sn = 0.f;
        float sv[16];
#pragma unroll
        for (int o = 0; o < 16; ++o) {
            float tacc = wred[0][o];
#pragma unroll
            for (int w = 1; w < 6; ++w) tacc += wred[w][o];
            sv[o] = tacc * inv;
            sn = fmaf(sv[o], sv[o], sn);
        }
        float scale = (sn / (1.f + sn)) / sqrtf(sn);
#pragma unroll
        for (int o = 0; o < 16; ++o) vout[o] = sv[o] * scale;
        float d0 = 0.f, d1 = 0.f, d2 = 0.f;
#pragma unroll
        for (int o = 0; o < 16; ++o) {
            d0 = fmaf(pr[0][o], vout[o], d0);
            d1 = fmaf(pr[1][o], vout[o], d1);
            d2 = fmaf(pr[2][o], vout[o], d2);
        }
        l0 = d0; l1 = d1; l2 = d2;
        __syncthreads();                 // wred reused next iteration
    }

    // ---- iterations 1,2: full softmax path ----
    for (int it = 1; it < 3; ++it) {
        float lm = fmaxf(fmaxf(l0, l1), l2);
#pragma unroll
        for (int m = 32; m >= 1; m >>= 1) lm = fmaxf(lm, __shfl_xor(lm, m));
        if (lane == 0) wred[wid][17] = lm;
        __syncthreads();
        float maxv = wred[0][17];
#pragma unroll
        for (int w = 1; w < 6; ++w) maxv = fmaxf(maxv, wred[w][17]);

        float e0 = expf(l0 - maxv), e1 = expf(l1 - maxv), e2 = expf(l2 - maxv);
        float red[17];
#pragma unroll
        for (int o = 0; o < 16; ++o)
            red[o] = fmaf(e0, pr[0][o], fmaf(e1, pr[1][o], e2 * pr[2][o]));
        red[16] = e0 + e1 + e2;
#pragma unroll
        for (int o = 0; o < 17; ++o) {
#pragma unroll
            for (int m = 32; m >= 1; m >>= 1) red[o] += __shfl_xor(red[o], m);
        }
        __syncthreads();
        if (lane == 0) {
#pragma unroll
            for (int o = 0; o < 17; ++o) wred[wid][o] = red[o];
        }
        __syncthreads();
        float sv[17];
#pragma unroll
        for (int o = 0; o < 17; ++o) {
            float tacc = wred[0][o];
#pragma unroll
            for (int w = 1; w < 6; ++w) tacc += wred[w][o];
            sv[o] = tacc;
        }
        float inv = 1.f / sv[16];
        float sn = 0.f;
#pragma unroll
        for (int o = 0; o < 16; ++o) { float s = sv[o] * inv; sn = fmaf(s, s, sn); }
        float scale = (sn / (1.f + sn)) / sqrtf(sn);
#pragma unroll
        for (int o = 0; o < 16; ++o) vout[o] = sv[o] * inv * scale;

        if (it < 2) {
            float d0 = 0.f, d1 = 0.f, d2 = 0.f;
#pragma unroll
            for (int o = 0; o < 16; ++o) {
                d0 = fmaf(pr[0][o], vout[o], d0);
                d1 = fmaf(pr[1][o], vout[o], d1);
                d2 = fmaf(pr[2][o], vout[o], d2);
            }
            l0 += d0; l1 += d1; l2 += d2;
        }
    }
    if (tid < 16) vbuf[(b * 10 + c) * 16 + tid] = vout[tid];
}

// --------------------------------------------------------------------------
// dec1: fused classes/argmax/y_pred + sparse masked GEMM (K=16 of 160).
__global__ __launch_bounds__(512) void dec1_k(const float* __restrict__ vbuf,
                                              const float* __restrict__ dw1,
                                              const float* __restrict__ db1,
                                              float* __restrict__ out,
                                              float* __restrict__ d1) {
    __shared__ float sv[160];
    __shared__ float scls[10];
    __shared__ int sbest;
    int b = blockIdx.x, tid = threadIdx.x;
    if (tid < 160) sv[tid] = vbuf[b * 160 + tid];
    __syncthreads();
    if (tid < 10) {
        float sn = 0.f;
#pragma unroll
        for (int o = 0; o < 16; ++o) { float v = sv[tid * 16 + o]; sn = fmaf(v, v, sn); }
        scls[tid] = sqrtf(sn);
    }
    __syncthreads();
    if (tid == 0) {
        int best = 0; float bv = scls[0];
#pragma unroll
        for (int cc = 1; cc < 10; ++cc) if (scls[cc] > bv) { bv = scls[cc]; best = cc; }
        sbest = best;
    }
    __syncthreads();
    int best = sbest;
    if (tid < 10) {
        out[b * 10 + tid] = (tid == best) ? 1.f : 0.f;          // y_pred
        out[406528 + b * 10 + tid] = scls[tid];                 // classes
    }
    float acc = db1[tid];
    const float* wrow = dw1 + (long)best * 16 * 512;
#pragma unroll
    for (int i = 0; i < 16; ++i)
        acc = fmaf(sv[best * 16 + i], wrow[i * 512 + tid], acc);
    d1[(long)b * 512 + tid] = fmaxf(acc, 0.f);
}

// --------------------------------------------------------------------------
template <int ACT>
__global__ __launch_bounds__(256) void dec_gemm(const float* __restrict__ A,
                                                const float* __restrict__ Bw,
                                                const float* __restrict__ bias,
                                                float* __restrict__ C,
                                                int M, int N, int K) {
    __shared__ float As[16][68];
    __shared__ float Bs[16][68];
    int ntiles = (N + 63) >> 6;
    int mt = blockIdx.x / ntiles, nt = blockIdx.x - mt * ntiles;
    int m0 = mt * 64, n0 = nt * 64;
    int tid = threadIdx.x;
    int tx = tid & 15, ty = tid >> 4;
    int am = tid >> 2, ak = (tid & 3) * 4;
    int bk = tid >> 4, bn = (tid & 15) * 4;
    float acc[4][4];
#pragma unroll
    for (int i = 0; i < 4; ++i)
#pragma unroll
        for (int j = 0; j < 4; ++j) acc[i][j] = 0.f;

    for (int k0 = 0; k0 < K; k0 += 16) {
        float4 av = *(const float4*)(A + (m0 + am) * K + k0 + ak);
        float4 bv = make_float4(0.f, 0.f, 0.f, 0.f);
        if (n0 + bn < N) bv = *(const float4*)(Bw + (k0 + bk) * N + n0 + bn);
        __syncthreads();
        As[ak + 0][am] = av.x;
        As[ak + 1][am] = av.y;
        As[ak + 2][am] = av.z;
        As[ak + 3][am] = av.w;
        *(float4*)&Bs[bk][bn] = bv;
        __syncthreads();
#pragma unroll
        for (int kk = 0; kk < 16; ++kk) {
            float4 a = *(const float4*)&As[kk][ty * 4];
            float4 bb = *(const float4*)&Bs[kk][tx * 4];
            float aa[4] = {a.x, a.y, a.z, a.w};
            float bbb[4] = {bb.x, bb.y, bb.z, bb.w};
#pragma unroll
            for (int i = 0; i < 4; ++i)
#pragma unroll
                for (int j = 0; j < 4; ++j)
                    acc[i][j] = fmaf(aa[i], bbb[j], acc[i][j]);
        }
    }
#pragma unroll
    for (int i = 0; i < 4; ++i) {
        int m = m0 + ty * 4 + i;
#pragma unroll
        for (int j = 0; j < 4; ++j) {
            int n = n0 + tx * 4 + j;
            if (n < N) {
                float v = acc[i][j] + bias[n];
                if (ACT == 0) v = fmaxf(v, 0.f);
                else          v = 1.f / (1.f + expf(-v));
                C[m * N + n] = v;
            }
        }
    }
}

// --------------------------------------------------------------------------
extern "C" void kernel_launch(void* const* d_in, const int* in_sizes, int n_in,
                              void* d_out, int out_size, void* d_ws, size_t ws_size,
                              hipStream_t stream) {
    const float* x   = (const float*)d_in[0];
    const float* w1  = (const float*)d_in[1];
    const float* b1  = (const float*)d_in[2];
    const float* pw  = (const float*)d_in[3];
    const float* pb  = (const float*)d_in[4];
    const float* rw  = (const float*)d_in[5];
    const float* dw1 = (const float*)d_in[6];
    const float* db1 = (const float*)d_in[7];
    const float* dw2 = (const float*)d_in[8];
    const float* db2 = (const float*)d_in[9];
    const float* dw3 = (const float*)d_in[10];
    const float* db3 = (const float*)d_in[11];
    float* out = (float*)d_out;
    char* wsb  = (char*)d_ws;
    if (ws_size < (size_t)WS_BYTES) return;

    h16*   hhi  = (h16*)(wsb + OFFB_HHI);
    h16*   rwh  = (h16*)(wsb + OFFB_RWH);
    h16*   ut   = (h16*)(wsb + OFFB_UT);
    h16*   wthi = (h16*)(wsb + OFFB_WTHI);
    h16*   w1t  = (h16*)(wsb + OFFB_WT1);
    float* Cbuf = (float*)(wsb + OFFB_C);
    float* vbuf = (float*)(wsb + OFFB_V);
    float* d1   = (float*)(wsb + OFFB_D1);
    float* d2   = (float*)(wsb + OFFB_D2);

    prep_k<<<24544, 256, 0, stream>>>(w1, pw, rw, w1t, wthi, rwh, Cbuf);
    conv1_mfma<<<3200, 256, 0, stream>>>(x, w1t, b1, hhi);
    prim_gemm_mfma<<<2304, 256, 0, stream>>>(hhi, wthi, Cbuf);
    squash_k<<<2304, 256, 0, stream>>>(Cbuf, pb, ut);
    routing3_k<<<5120, 384, 0, stream>>>(ut, rwh, vbuf);
    dec1_k<<<512, 512, 0, stream>>>(vbuf, dw1, db1, out, d1);
    dec_gemm<0><<<128, 256, 0, stream>>>(d1, dw2, db2, d2, 512, 1024, 512);
    dec_gemm<1><<<104, 256, 0, stream>>>(d2, dw3, db3, out + 5120, 512, 784, 1024);
}

// Round 18
// 866.613 us; speedup vs baseline: 1.1848x; 1.1848x over previous
//
#include <hip/hip_runtime.h>
#include <math.h>

// ---------------------------------------------------------------------------
// CapsuleNet forward (round 18): revert to round-16 (best: 873.6 us).
// Round-17's fused routing3 regressed (400 us: 5120 blocks re-reading rw
// slices from L2 at full latency beat the 189 MB HBM round-trip it saved).
// Two-phase routing restored. All components are individually measured:
//  - prim: round-7 body, (256,4), splitK8 kt->XCD   [342 us; 8 variants lost]
//  - conv1: MFMA implicit im2col                     [round 13]
//  - priors_k/routing2_k two-phase + it0 shortcut    [rounds 6/12/14]
//  - dec1 fused argmax+sparse GEMM, prep_k fused     [round 12]
// ---------------------------------------------------------------------------

typedef _Float16 h16;
typedef h16 frag8 __attribute__((ext_vector_type(8)));    // 8 halves = 16 B
typedef float f32x4 __attribute__((ext_vector_type(4)));

// workspace layout (BYTE offsets).
#define OFFB_HHI   0L             // 52428800 halves = 104857600 B
#define OFFB_WTHI  209715200L     // 5308416 halves = 10616832 B
#define OFFB_WT1   230948864L     // w1t: 24576 halves = 49152 B
#define OFFB_C     231031808L     // 4718592 floats -> end 249906176
#define WS_BYTES   249906176L
// aliased into dead h region after prim_gemm:
#define OFFB_PRI   0L             // 94371840 halves = 188743680 B (priors fp16)
#define OFFB_UT    188743680L     // 4718592 halves = 9437184 B -> OK
// aliased into dead wt region after prim_gemm:
#define OFFB_V     209715200L     // 81920 floats
#define OFFB_D1    210370560L     // 262144 floats
#define OFFB_D2    211419136L     // 524288 floats -> 213516288 OK

// --------------------------------------------------------------------------
// prep: blocks 0..95: w1t[oc][96] fp16 (k-padded); 96..351: prim B^T fp16;
// 352..18783: zero C.
__global__ __launch_bounds__(256) void prep_k(const float* __restrict__ w1,
                                              const float* __restrict__ pw,
                                              h16* __restrict__ w1t,
                                              h16* __restrict__ whi,
                                              float* __restrict__ C) {
    __shared__ float s[2592];
    int bx = blockIdx.x, tid = threadIdx.x;
    if (bx < 96) {
        int k = bx, oc = tid;
        w1t[(long)oc * 96 + k] = (k < 81) ? (h16)w1[oc * 81 + k] : (h16)0.f;
    } else if (bx < 352) {
        int oc = bx - 96;
        long src0 = (long)oc * 20736, dst0 = src0;
        for (int ch = 0; ch < 8; ++ch) {
            int ic0 = ch * 32;
            __syncthreads();
            for (int e = tid; e < 2592; e += 256) s[e] = pw[src0 + ic0 * 81 + e];
            __syncthreads();
            for (int e = tid; e < 2592; e += 256) {
                int tap = e >> 5, icf = e & 31;
                whi[dst0 + tap * 256 + ic0 + icf] = (h16)s[icf * 81 + tap];
            }
        }
    } else {
        long i = (long)(bx - 352) * 256 + tid;   // 18432 blocks * 256 = 4718592
        C[i] = 0.f;
    }
}

// --------------------------------------------------------------------------
// conv1 as MFMA implicit-im2col GEMM. Grid 3200: nt = bx&1, mt = bx>>1.
#define CLDK 104
__global__ __launch_bounds__(256, 2) void conv1_mfma(const float* __restrict__ x,
                                                     const h16* __restrict__ w1t,
                                                     const float* __restrict__ bias,
                                                     h16* __restrict__ hhi) {
    __shared__ h16 Al[128 * CLDK];
    __shared__ h16 Bw[128 * CLDK];
    int tid = threadIdx.x;
    int bx = blockIdx.x;
    int nt = bx & 1, mt = bx >> 1;
    int n0 = nt * 128;

    for (int e = tid; e < 128 * 96; e += 256) {
        int oc = e / 96, k = e - (e / 96) * 96;
        Bw[oc * CLDK + k] = w1t[(long)(n0 + oc) * 96 + k];
    }
    for (int e = tid; e < 128 * 96; e += 256) {
        int ml = e / 96, k = e - (e / 96) * 96;
        int m = mt * 128 + ml;
        int b = m / 400, pix = m - b * 400;
        int oy = pix / 20, ox = pix - oy * 20;
        float v = 0.f;
        if (k < 81) {
            int ky = k / 9, kx = k - ky * 9;
            v = x[(long)b * 784 + (oy + ky) * 28 + (ox + kx)];
        }
        Al[ml * CLDK + k] = (h16)v;
    }
    __syncthreads();

    int wave = tid >> 6;
    int wm = wave >> 1, wn = wave & 1;
    int lane = tid & 63;
    int lm = lane & 15, quad = lane >> 4;

    f32x4 acc[4][4];
#pragma unroll
    for (int i = 0; i < 4; ++i)
#pragma unroll
        for (int j = 0; j < 4; ++j) acc[i][j] = (f32x4){0.f, 0.f, 0.f, 0.f};

#pragma unroll
    for (int ks = 0; ks < 3; ++ks) {
        int kc = ks * 32 + quad * 8;
        frag8 af[4], bf[4];
#pragma unroll
        for (int mi = 0; mi < 4; ++mi)
            af[mi] = *(const frag8*)&Al[(wm * 64 + mi * 16 + lm) * CLDK + kc];
#pragma unroll
        for (int ni = 0; ni < 4; ++ni)
            bf[ni] = *(const frag8*)&Bw[(wn * 64 + ni * 16 + lm) * CLDK + kc];
#pragma unroll
        for (int mi = 0; mi < 4; ++mi)
#pragma unroll
            for (int ni = 0; ni < 4; ++ni)
                acc[mi][ni] = __builtin_amdgcn_mfma_f32_16x16x32_f16(
                    af[mi], bf[ni], acc[mi][ni], 0, 0, 0);
    }

#pragma unroll
    for (int ni = 0; ni < 4; ++ni) {
        int oc = n0 + wn * 64 + ni * 16 + lm;
        float bv = bias[oc];
#pragma unroll
        for (int mi = 0; mi < 4; ++mi) {
            int m = mt * 128 + wm * 64 + mi * 16 + quad * 4;
#pragma unroll
            for (int r = 0; r < 4; ++r)
                hhi[(long)(m + r) * 256 + oc] = (h16)fmaxf(acc[mi][ni][r] + bv, 0.f);
        }
    }
}

// --------------------------------------------------------------------------
// prim conv MFMA GEMM (round-7 body, proven 340 us): BM=128 BN=128 BK=32,
// split-K x8 (kt = bx&7 -> XCD-pinned B slice), fp16 single pass,
// register-prefetch staging, atomic accumulate into zeroed C. 4 waves/EU.
#define LDK 40
__global__ __launch_bounds__(256, 4) void prim_gemm_mfma(
        const h16* __restrict__ Ahi, const h16* __restrict__ Bhi,
        float* __restrict__ C) {
    __shared__ h16 As[128][LDK];
    __shared__ h16 Bs[128][LDK];
    int tid = threadIdx.x;
    int bx = blockIdx.x;                  // 2304 blocks
    int kt = bx & 7;
    int nt = (bx >> 3) & 1;
    int mt = bx >> 4;                     // 0..143
    int n0 = nt * 128;
    int kb0 = kt * 81;

    int wave = tid >> 6;
    int wm = wave >> 1, wn = wave & 1;
    int lane = tid & 63;
    int lm = lane & 15, quad = lane >> 4;

    int ra = tid >> 1;
    int sa = (tid & 1) * 16;
    int ma = mt * 128 + ra;
    int b = ma / 36, pos = ma - b * 36;
    int oy = pos / 6, ox = pos - oy * 6;
    long abase = ((long)(b * 20 + 2 * oy) * 20 + 2 * ox) * 256 + sa;
    long bbase = (long)(n0 + ra) * 20736 + sa;

    float4 pa0, pa1, pb0, pb1;
    auto gload = [&](int kb) {
        int tap = kb >> 3;
        int ic0 = (kb & 7) << 5;
        int ky = tap / 9, kx = tap - ky * 9;
        long aoff = abase + (ky * 20 + kx) * 256 + ic0;
        pa0 = *(const float4*)(Ahi + aoff);
        pa1 = *(const float4*)(Ahi + aoff + 8);
        long boff = bbase + (long)kb * 32;
        pb0 = *(const float4*)(Bhi + boff);
        pb1 = *(const float4*)(Bhi + boff + 8);
    };

    f32x4 acc[4][4];
#pragma unroll
    for (int i = 0; i < 4; ++i)
#pragma unroll
        for (int j = 0; j < 4; ++j) acc[i][j] = (f32x4){0.f, 0.f, 0.f, 0.f};

    gload(kb0);
    for (int it = 0; it < 81; ++it) {
        __syncthreads();
        *(float4*)&As[ra][sa]     = pa0;
        *(float4*)&As[ra][sa + 8] = pa1;
        *(float4*)&Bs[ra][sa]     = pb0;
        *(float4*)&Bs[ra][sa + 8] = pb1;
        __syncthreads();
        if (it + 1 < 81) gload(kb0 + it + 1);

        frag8 ah[4], bh[4];
#pragma unroll
        for (int mi = 0; mi < 4; ++mi) {
            int row = wm * 64 + mi * 16 + lm;
            ah[mi] = *(const frag8*)&As[row][quad * 8];
        }
#pragma unroll
        for (int ni = 0; ni < 4; ++ni) {
            int col = wn * 64 + ni * 16 + lm;
            bh[ni] = *(const frag8*)&Bs[col][quad * 8];
        }
#pragma unroll
        for (int mi = 0; mi < 4; ++mi)
#pragma unroll
            for (int ni = 0; ni < 4; ++ni)
                acc[mi][ni] = __builtin_amdgcn_mfma_f32_16x16x32_f16(
                    ah[mi], bh[ni], acc[mi][ni], 0, 0, 0);
    }

#pragma unroll
    for (int ni = 0; ni < 4; ++ni) {
        int n = n0 + wn * 64 + ni * 16 + lm;
#pragma unroll
        for (int mi = 0; mi < 4; ++mi) {
            int m = mt * 128 + wm * 64 + mi * 16 + quad * 4;
#pragma unroll
            for (int r = 0; r < 4; ++r)
                atomicAdd(&C[(long)(m + r) * 256 + n], acc[mi][ni][r]);
        }
    }
}

// --------------------------------------------------------------------------
// squash: C[(b*36+pos)][256] (+bias) -> ut[n][b][8] fp16, n = ci*36+pos.
__global__ void squash_k(const float* __restrict__ C,
                         const float* __restrict__ bias,
                         h16* __restrict__ ut) {
    int t = blockIdx.x * 256 + threadIdx.x;          // 589824 exact
    int row = t >> 5;                                 // (b*36+pos)
    int ci = t & 31;
    int b = row / 36, pos = row - b * 36;
    const float* src = C + (long)row * 256 + ci;
    float v[8]; float sn = 0.f;
#pragma unroll
    for (int i = 0; i < 8; ++i) {
        v[i] = src[i * 32] + bias[ci + i * 32];
        sn = fmaf(v[i], v[i], sn);
    }
    float scale = (sn / (1.f + sn)) / sqrtf(sn);
    frag8 o;
#pragma unroll
    for (int i = 0; i < 8; ++i) o[i] = (h16)(v[i] * scale);
    *(frag8*)(ut + ((long)(ci * 36 + pos) * 512 + b) * 8) = o;
}

// --------------------------------------------------------------------------
// Phase A: priors[c,b,n,:16] = ut[n,b,:8] @ rw[c,n,:8,:16], fp16 out.
__global__ __launch_bounds__(256) void priors_k(const h16* __restrict__ ut,
                                                const float* __restrict__ rw,
                                                h16* __restrict__ priors) {
    int bid = blockIdx.x;                 // 1440 = 10 c * 144 n-groups
    int c = bid / 144, ng = bid - c * 144;
    int n0 = ng * 8;
    __shared__ float w[8][132];
    int tid = threadIdx.x;
    for (int e = tid; e < 1024; e += 256)
        w[e >> 7][e & 127] = rw[((long)c * 1152 + n0 + (e >> 7)) * 128 + (e & 127)];
    __syncthreads();
    int nl = tid & 7, bl = tid >> 3;      // bl 0..31
    int n = n0 + nl;
    for (int ch = 0; ch < 16; ++ch) {
        int b = ch * 32 + bl;
        frag8 uv = *(const frag8*)(ut + ((long)n * 512 + b) * 8);
        float uu[8];
#pragma unroll
        for (int i = 0; i < 8; ++i) uu[i] = (float)uv[i];
        float o[16];
#pragma unroll
        for (int j = 0; j < 16; ++j) o[j] = 0.f;
#pragma unroll
        for (int i = 0; i < 8; ++i)
#pragma unroll
            for (int j = 0; j < 16; ++j)
                o[j] = fmaf(uu[i], w[nl][i * 16 + j], o[j]);
        frag8 p0, p1;
#pragma unroll
        for (int j = 0; j < 8; ++j) { p0[j] = (h16)o[j]; p1[j] = (h16)o[j + 8]; }
        h16* dst = priors + ((long)(c * 512 + b) * 1152 + n) * 16;
        *(frag8*)dst = p0;
        *(frag8*)(dst + 8) = p1;
    }
}

// --------------------------------------------------------------------------
// Phase B: 3-iter routing. Block per (c,b). Iteration 0 uses the exact
// uniform-softmax shortcut (initial logits identically 0 -> probs = 1/1152).
__global__ __launch_bounds__(384) void routing2_k(const h16* __restrict__ priors,
                                                  float* __restrict__ vbuf) {
    int c = blockIdx.x >> 9;
    int b = blockIdx.x & 511;
    int tid = threadIdx.x;
    int wid = tid >> 6;
    int lane = tid & 63;
    __shared__ float wred[6][20];

    float pr[3][16];
#pragma unroll
    for (int r = 0; r < 3; ++r) {
        int n = tid + r * 384;
        const h16* pp = priors + ((long)(c * 512 + b) * 1152 + n) * 16;
        frag8 p0 = *(const frag8*)pp;
        frag8 p1 = *(const frag8*)(pp + 8);
#pragma unroll
        for (int o = 0; o < 8; ++o) { pr[r][o] = (float)p0[o]; pr[r][o + 8] = (float)p1[o]; }
    }

    float l0 = 0.f, l1 = 0.f, l2 = 0.f;
    float vout[16];

    // ---- iteration 0: probs uniform = 1/1152 ----
    {
        float red[16];
#pragma unroll
        for (int o = 0; o < 16; ++o) red[o] = pr[0][o] + pr[1][o] + pr[2][o];
#pragma unroll
        for (int o = 0; o < 16; ++o) {
#pragma unroll
            for (int m = 32; m >= 1; m >>= 1) red[o] += __shfl_xor(red[o], m);
        }
        if (lane == 0) {
#pragma unroll
            for (int o = 0; o < 16; ++o) wred[wid][o] = red[o];
        }
        __syncthreads();
        float inv = 1.f / 1152.f;
        float sn = 0.f;
        float sv[16];
#pragma unroll
        for (int o = 0; o < 16; ++o) {
            float tacc = wred[0][o];
#pragma unroll
            for (int w = 1; w < 6; ++w) tacc += wred[w][o];
            sv[o] = tacc * inv;
            sn = fmaf(sv[o], sv[o], sn);
        }
        float scale = (sn / (1.f + sn)) / sqrtf(sn);
#pragma unroll
        for (int o = 0; o < 16; ++o) vout[o] = sv[o] * scale;
        float d0 = 0.f, d1 = 0.f, d2 = 0.f;
#pragma unroll
        for (int o = 0; o < 16; ++o) {
            d0 = fmaf(pr[0][o], vout[o], d0);
            d1 = fmaf(pr[1][o], vout[o], d1);
            d2 = fmaf(pr[2][o], vout[o], d2);
        }
        l0 = d0; l1 = d1; l2 = d2;
        __syncthreads();                 // wred reused next iteration
    }

    // ---- iterations 1,2: full softmax path ----
    for (int it = 1; it < 3; ++it) {
        float lm = fmaxf(fmaxf(l0, l1), l2);
#pragma unroll
        for (int m = 32; m >= 1; m >>= 1) lm = fmaxf(lm, __shfl_xor(lm, m));
        if (lane == 0) wred[wid][17] = lm;
        __syncthreads();
        float maxv = wred[0][17];
#pragma unroll
        for (int w = 1; w < 6; ++w) maxv = fmaxf(maxv, wred[w][17]);

        float e0 = expf(l0 - maxv), e1 = expf(l1 - maxv), e2 = expf(l2 - maxv);
        float red[17];
#pragma unroll
        for (int o = 0; o < 16; ++o)
            red[o] = fmaf(e0, pr[0][o], fmaf(e1, pr[1][o], e2 * pr[2][o]));
        red[16] = e0 + e1 + e2;
#pragma unroll
        for (int o = 0; o < 17; ++o) {
#pragma unroll
            for (int m = 32; m >= 1; m >>= 1) red[o] += __shfl_xor(red[o], m);
        }
        __syncthreads();
        if (lane == 0) {
#pragma unroll
            for (int o = 0; o < 17; ++o) wred[wid][o] = red[o];
        }
        __syncthreads();
        float sv[17];
#pragma unroll
        for (int o = 0; o < 17; ++o) {
            float tacc = wred[0][o];
#pragma unroll
            for (int w = 1; w < 6; ++w) tacc += wred[w][o];
            sv[o] = tacc;
        }
        float inv = 1.f / sv[16];
        float sn = 0.f;
#pragma unroll
        for (int o = 0; o < 16; ++o) { float s = sv[o] * inv; sn = fmaf(s, s, sn); }
        float scale = (sn / (1.f + sn)) / sqrtf(sn);
#pragma unroll
        for (int o = 0; o < 16; ++o) vout[o] = sv[o] * inv * scale;

        if (it < 2) {
            float d0 = 0.f, d1 = 0.f, d2 = 0.f;
#pragma unroll
            for (int o = 0; o < 16; ++o) {
                d0 = fmaf(pr[0][o], vout[o], d0);
                d1 = fmaf(pr[1][o], vout[o], d1);
                d2 = fmaf(pr[2][o], vout[o], d2);
            }
            l0 += d0; l1 += d1; l2 += d2;
        }
    }
    if (tid < 16) vbuf[(b * 10 + c) * 16 + tid] = vout[tid];
}

// --------------------------------------------------------------------------
// dec1: fused classes/argmax/y_pred + sparse masked GEMM (K=16 of 160).
__global__ __launch_bounds__(512) void dec1_k(const float* __restrict__ vbuf,
                                              const float* __restrict__ dw1,
                                              const float* __restrict__ db1,
                                              float* __restrict__ out,
                                              float* __restrict__ d1) {
    __shared__ float sv[160];
    __shared__ float scls[10];
    __shared__ int sbest;
    int b = blockIdx.x, tid = threadIdx.x;
    if (tid < 160) sv[tid] = vbuf[b * 160 + tid];
    __syncthreads();
    if (tid < 10) {
        float sn = 0.f;
#pragma unroll
        for (int o = 0; o < 16; ++o) { float v = sv[tid * 16 + o]; sn = fmaf(v, v, sn); }
        scls[tid] = sqrtf(sn);
    }
    __syncthreads();
    if (tid == 0) {
        int best = 0; float bv = scls[0];
#pragma unroll
        for (int cc = 1; cc < 10; ++cc) if (scls[cc] > bv) { bv = scls[cc]; best = cc; }
        sbest = best;
    }
    __syncthreads();
    int best = sbest;
    if (tid < 10) {
        out[b * 10 + tid] = (tid == best) ? 1.f : 0.f;          // y_pred
        out[406528 + b * 10 + tid] = scls[tid];                 // classes
    }
    float acc = db1[tid];
    const float* wrow = dw1 + (long)best * 16 * 512;
#pragma unroll
    for (int i = 0; i < 16; ++i)
        acc = fmaf(sv[best * 16 + i], wrow[i * 512 + tid], acc);
    d1[(long)b * 512 + tid] = fmaxf(acc, 0.f);
}

// --------------------------------------------------------------------------
template <int ACT>
__global__ __launch_bounds__(256) void dec_gemm(const float* __restrict__ A,
                                                const float* __restrict__ Bw,
                                                const float* __restrict__ bias,
                                                float* __restrict__ C,
                                                int M, int N, int K) {
    __shared__ float As[16][68];
    __shared__ float Bs[16][68];
    int ntiles = (N + 63) >> 6;
    int mt = blockIdx.x / ntiles, nt = blockIdx.x - mt * ntiles;
    int m0 = mt * 64, n0 = nt * 64;
    int tid = threadIdx.x;
    int tx = tid & 15, ty = tid >> 4;
    int am = tid >> 2, ak = (tid & 3) * 4;
    int bk = tid >> 4, bn = (tid & 15) * 4;
    float acc[4][4];
#pragma unroll
    for (int i = 0; i < 4; ++i)
#pragma unroll
        for (int j = 0; j < 4; ++j) acc[i][j] = 0.f;

    for (int k0 = 0; k0 < K; k0 += 16) {
        float4 av = *(const float4*)(A + (m0 + am) * K + k0 + ak);
        float4 bv = make_float4(0.f, 0.f, 0.f, 0.f);
        if (n0 + bn < N) bv = *(const float4*)(Bw + (k0 + bk) * N + n0 + bn);
        __syncthreads();
        As[ak + 0][am] = av.x;
        As[ak + 1][am] = av.y;
        As[ak + 2][am] = av.z;
        As[ak + 3][am] = av.w;
        *(float4*)&Bs[bk][bn] = bv;
        __syncthreads();
#pragma unroll
        for (int kk = 0; kk < 16; ++kk) {
            float4 a = *(const float4*)&As[kk][ty * 4];
            float4 bb = *(const float4*)&Bs[kk][tx * 4];
            float aa[4] = {a.x, a.y, a.z, a.w};
            float bbb[4] = {bb.x, bb.y, bb.z, bb.w};
#pragma unroll
            for (int i = 0; i < 4; ++i)
#pragma unroll
                for (int j = 0; j < 4; ++j)
                    acc[i][j] = fmaf(aa[i], bbb[j], acc[i][j]);
        }
    }
#pragma unroll
    for (int i = 0; i < 4; ++i) {
        int m = m0 + ty * 4 + i;
#pragma unroll
        for (int j = 0; j < 4; ++j) {
            int n = n0 + tx * 4 + j;
            if (n < N) {
                float v = acc[i][j] + bias[n];
                if (ACT == 0) v = fmaxf(v, 0.f);
                else          v = 1.f / (1.f + expf(-v));
                C[m * N + n] = v;
            }
        }
    }
}

// --------------------------------------------------------------------------
extern "C" void kernel_launch(void* const* d_in, const int* in_sizes, int n_in,
                              void* d_out, int out_size, void* d_ws, size_t ws_size,
                              hipStream_t stream) {
    const float* x   = (const float*)d_in[0];
    const float* w1  = (const float*)d_in[1];
    const float* b1  = (const float*)d_in[2];
    const float* pw  = (const float*)d_in[3];
    const float* pb  = (const float*)d_in[4];
    const float* rw  = (const float*)d_in[5];
    const float* dw1 = (const float*)d_in[6];
    const float* db1 = (const float*)d_in[7];
    const float* dw2 = (const float*)d_in[8];
    const float* db2 = (const float*)d_in[9];
    const float* dw3 = (const float*)d_in[10];
    const float* db3 = (const float*)d_in[11];
    float* out = (float*)d_out;
    char* wsb  = (char*)d_ws;
    if (ws_size < (size_t)WS_BYTES) return;

    h16*   hhi  = (h16*)(wsb + OFFB_HHI);
    h16*   wthi = (h16*)(wsb + OFFB_WTHI);
    h16*   w1t  = (h16*)(wsb + OFFB_WT1);
    float* Cbuf = (float*)(wsb + OFFB_C);
    h16*   pri  = (h16*)(wsb + OFFB_PRI);
    h16*   ut   = (h16*)(wsb + OFFB_UT);
    float* vbuf = (float*)(wsb + OFFB_V);
    float* d1   = (float*)(wsb + OFFB_D1);
    float* d2   = (float*)(wsb + OFFB_D2);

    prep_k<<<18784, 256, 0, stream>>>(w1, pw, w1t, wthi, Cbuf);
    conv1_mfma<<<3200, 256, 0, stream>>>(x, w1t, b1, hhi);
    prim_gemm_mfma<<<2304, 256, 0, stream>>>(hhi, wthi, Cbuf);
    squash_k<<<2304, 256, 0, stream>>>(Cbuf, pb, ut); // h region dead now
    priors_k<<<1440, 256, 0, stream>>>(ut, rw, pri);
    routing2_k<<<5120, 384, 0, stream>>>(pri, vbuf);
    dec1_k<<<512, 512, 0, stream>>>(vbuf, dw1, db1, out, d1);
    dec_gemm<0><<<128, 256, 0, stream>>>(d1, dw2, db2, d2, 512, 1024, 512);
    dec_gemm<1><<<104, 256, 0, stream>>>(d2, dw3, db3, out + 5120, 512, 784, 1024);
}